// Round 1
// baseline (2589.290 us; speedup 1.0000x reference)
//
#include <hip/hip_runtime.h>
#include <math.h>

#define NB 8
#define NC 256
#define NHW 2304
#define NG 32
#define CPG 8            // NC / NG
#define GN_EPS 1e-5f
#define ATT_SCALE 0.0625f  // 1/sqrt(256)

// ---------------------------------------------------------------------------
// Kernel 1: GroupNorm statistics -> per-channel scale/shift
//   xn[b,c,p] = x[b,c,p]*scale[b,c] + shift[b,c]
// grid: NB*NG blocks, 256 threads. Group data is contiguous (CPG*NHW floats).
// ---------------------------------------------------------------------------
__global__ __launch_bounds__(256) void k_gn_stats(
    const float* __restrict__ x, const float* __restrict__ gn_w,
    const float* __restrict__ gn_b, float* __restrict__ scale,
    float* __restrict__ shift) {
  int bg = blockIdx.x;  // b*NG + g
  const float4* base = (const float4*)(x + (size_t)bg * CPG * NHW);
  const int n4 = CPG * NHW / 4;  // 4608
  float s = 0.f, ss = 0.f;
  for (int i = threadIdx.x; i < n4; i += 256) {
    float4 v = base[i];
    s  += v.x + v.y + v.z + v.w;
    ss += v.x * v.x + v.y * v.y + v.z * v.z + v.w * v.w;
  }
  for (int off = 32; off > 0; off >>= 1) {
    s  += __shfl_down(s, off);
    ss += __shfl_down(ss, off);
  }
  __shared__ float red[8];
  int wv = threadIdx.x >> 6, ln = threadIdx.x & 63;
  if (ln == 0) { red[wv] = s; red[4 + wv] = ss; }
  __syncthreads();
  if (threadIdx.x < CPG) {
    float S  = red[0] + red[1] + red[2] + red[3];
    float SS = red[4] + red[5] + red[6] + red[7];
    const float inv_n = 1.f / (float)(CPG * NHW);
    float mean = S * inv_n;
    float var  = SS * inv_n - mean * mean;
    float rstd = rsqrtf(var + GN_EPS);
    int b = bg / NG, g = bg % NG;
    int c = g * CPG + threadIdx.x;
    float sc = gn_w[c] * rstd;
    scale[b * NC + c] = sc;
    shift[b * NC + c] = gn_b[c] - mean * sc;
  }
}

// ---------------------------------------------------------------------------
// Kernel 2: fused GN + 1x1 conv (three GEMMs): out[b,o,p] = sum_c W[o,c]*xn + bias
// grid: (NHW/64, NC/64, NB*3), block 256 (16x16), 64x64 tile, K-chunks of 16.
// ---------------------------------------------------------------------------
__global__ __launch_bounds__(256) void k_qkv(
    const float* __restrict__ x,
    const float* __restrict__ Wq, const float* __restrict__ bq,
    const float* __restrict__ Wk, const float* __restrict__ bk,
    const float* __restrict__ Wv, const float* __restrict__ bv,
    const float* __restrict__ scale, const float* __restrict__ shift,
    float* __restrict__ qo, float* __restrict__ ko, float* __restrict__ vo) {
  __shared__ float wl[16 * 64];  // [c][o]
  __shared__ float xl[16 * 64];  // [c][p] (normalized)
  int p0 = blockIdx.x * 64;
  int o0 = blockIdx.y * 64;
  int b = blockIdx.z / 3;
  int which = blockIdx.z % 3;
  const float* W    = which == 0 ? Wq : (which == 1 ? Wk : Wv);
  const float* bias = which == 0 ? bq : (which == 1 ? bk : bv);
  float* out        = which == 0 ? qo : (which == 1 ? ko : vo);
  int tid = threadIdx.x;
  int tx = tid & 15, ty = tid >> 4;
  int lo = tid & 63;   // o / p index for loads
  int lc = tid >> 6;   // base c (0..3)
  float acc[4][4];
#pragma unroll
  for (int i = 0; i < 4; ++i)
#pragma unroll
    for (int j = 0; j < 4; ++j) acc[i][j] = 0.f;
  const float* xb = x + (size_t)b * NC * NHW;
  const float* scb = scale + b * NC;
  const float* shb = shift + b * NC;
  for (int c0 = 0; c0 < NC; c0 += 16) {
    __syncthreads();
#pragma unroll
    for (int r = 0; r < 4; ++r) {
      int c = lc + 4 * r;
      wl[c * 64 + lo] = W[(size_t)(o0 + lo) * NC + c0 + c];
      xl[c * 64 + lo] =
          xb[(size_t)(c0 + c) * NHW + p0 + lo] * scb[c0 + c] + shb[c0 + c];
    }
    __syncthreads();
#pragma unroll
    for (int kk = 0; kk < 16; ++kk) {
      float4 wv4 = *(const float4*)&wl[kk * 64 + 4 * ty];
      float4 xv4 = *(const float4*)&xl[kk * 64 + 4 * tx];
      float wr[4] = {wv4.x, wv4.y, wv4.z, wv4.w};
      float xr[4] = {xv4.x, xv4.y, xv4.z, xv4.w};
#pragma unroll
      for (int i = 0; i < 4; ++i)
#pragma unroll
        for (int j = 0; j < 4; ++j) acc[i][j] += wr[i] * xr[j];
    }
  }
#pragma unroll
  for (int i = 0; i < 4; ++i) {
    int o = o0 + 4 * ty + i;
    float bb = bias[o];
    float4 r;
    r.x = acc[i][0] + bb; r.y = acc[i][1] + bb;
    r.z = acc[i][2] + bb; r.w = acc[i][3] + bb;
    *(float4*)&out[((size_t)b * NC + o) * NHW + p0 + 4 * tx] = r;
  }
}

// ---------------------------------------------------------------------------
// Kernel 3: flash-style attention (fp32).
//   S = Q^T K / 16 ; P = exp(S) (energies are tiny -> no max subtraction
//   needed; softmax is shift-invariant so result matches reference)
//   out[c,j] = (sum_jk P[j,jk] V[c,jk]) / (sum_jk P[j,jk])
// grid: (NHW/64, NB), block 256 (16x16). TQ=64, TK=64.
// LDS: Q [256][64] 64KB, K/V union 65KB (K as [c][64], V as [jk][260] to make
// the AV inner loop read conflict-free), scores [64][65] 16.3KB. ~145.5KB.
// ---------------------------------------------------------------------------
__global__ __launch_bounds__(256, 1) void k_attn(
    const float* __restrict__ q, const float* __restrict__ k,
    const float* __restrict__ v, float* __restrict__ out) {
  extern __shared__ float sm[];
  float* ql = sm;               // [256][64]   16384
  float* kv = sm + 16384;       // K:[256][64] / V:[64][260]  16640
  float* sl = kv + 16640;       // [64][65]    4160
  float* ll = sl + 4160;        // [64]
  int q0 = blockIdx.x * 64;
  int b = blockIdx.y;
  int tid = threadIdx.x;
  int tx = tid & 15, ty = tid >> 4;
  const float* qb = q + (size_t)b * NC * NHW;
  const float* kb = k + (size_t)b * NC * NHW;
  const float* vb = v + (size_t)b * NC * NHW;
  // load Q tile (coalesced): ql[c][j]
  for (int i = tid; i < 256 * 64; i += 256) {
    ql[i] = qb[(size_t)(i >> 6) * NHW + q0 + (i & 63)];
  }
  float acc[4][4][4];  // [cc][r(j)][ci(c)]
#pragma unroll
  for (int a0 = 0; a0 < 4; ++a0)
#pragma unroll
    for (int a1 = 0; a1 < 4; ++a1)
#pragma unroll
      for (int a2 = 0; a2 < 4; ++a2) acc[a0][a1][a2] = 0.f;
  float li = 0.f;  // row-sum accumulator (threads 0..63 own row tid)

  for (int kt = 0; kt < NHW; kt += 64) {
    __syncthreads();  // protect kv/sl reuse from previous iteration
    // load K tile: kv[c][jk]
    for (int i = tid; i < 256 * 64; i += 256) {
      kv[i] = kb[(size_t)(i >> 6) * NHW + kt + (i & 63)];
    }
    __syncthreads();
    // scores: thread tile j in [4ty,4ty+4), jk in [4tx,4tx+4)
    float sr[4][4];
#pragma unroll
    for (int r = 0; r < 4; ++r)
#pragma unroll
      for (int i = 0; i < 4; ++i) sr[r][i] = 0.f;
    for (int c = 0; c < 256; ++c) {
      float4 qv4 = *(const float4*)&ql[c * 64 + 4 * ty];
      float4 kv4 = *(const float4*)&kv[c * 64 + 4 * tx];
      float qr[4] = {qv4.x, qv4.y, qv4.z, qv4.w};
      float kr[4] = {kv4.x, kv4.y, kv4.z, kv4.w};
#pragma unroll
      for (int r = 0; r < 4; ++r)
#pragma unroll
        for (int i = 0; i < 4; ++i) sr[r][i] += qr[r] * kr[i];
    }
#pragma unroll
    for (int r = 0; r < 4; ++r)
#pragma unroll
      for (int i = 0; i < 4; ++i)
        sl[(4 * ty + r) * 65 + 4 * tx + i] = expf(sr[r][i] * ATT_SCALE);
    __syncthreads();
    // load V tile transposed with pad: kv[jk][c] stride 260
    for (int i = tid; i < 256 * 64; i += 256) {
      kv[(i & 63) * 260 + (i >> 6)] =
          vb[(size_t)(i >> 6) * NHW + kt + (i & 63)];
    }
    // row sums (threads 0..63, conflict-free via stride 65)
    if (tid < 64) {
      float srow = 0.f;
      for (int i = 0; i < 64; ++i) srow += sl[tid * 65 + i];
      li += srow;
    }
    __syncthreads();
    // AV: acc[cc][r][ci] += P[4ty+r][jk] * V[4tx+64cc+ci][jk]
    for (int jk = 0; jk < 64; ++jk) {
      float pr[4];
#pragma unroll
      for (int r = 0; r < 4; ++r) pr[r] = sl[(4 * ty + r) * 65 + jk];
#pragma unroll
      for (int cc = 0; cc < 4; ++cc) {
        float4 vv4 = *(const float4*)&kv[jk * 260 + 4 * tx + 64 * cc];
        float vr[4] = {vv4.x, vv4.y, vv4.z, vv4.w};
#pragma unroll
        for (int r = 0; r < 4; ++r)
#pragma unroll
          for (int ci = 0; ci < 4; ++ci) acc[cc][r][ci] += pr[r] * vr[ci];
      }
    }
  }
  if (tid < 64) ll[tid] = li;
  __syncthreads();
  float inv[4];
#pragma unroll
  for (int r = 0; r < 4; ++r) inv[r] = 1.f / ll[4 * ty + r];
  float* ob = out + (size_t)b * NC * NHW;
#pragma unroll
  for (int cc = 0; cc < 4; ++cc)
#pragma unroll
    for (int ci = 0; ci < 4; ++ci) {
      int c = 4 * tx + 64 * cc + ci;
      float4 r4;
      r4.x = acc[cc][0][ci] * inv[0];
      r4.y = acc[cc][1][ci] * inv[1];
      r4.z = acc[cc][2][ci] * inv[2];
      r4.w = acc[cc][3][ci] * inv[3];
      *(float4*)&ob[(size_t)c * NHW + q0 + 4 * ty] = r4;
    }
}

// ---------------------------------------------------------------------------
extern "C" void kernel_launch(void* const* d_in, const int* in_sizes, int n_in,
                              void* d_out, int out_size, void* d_ws,
                              size_t ws_size, hipStream_t stream) {
  const float* x   = (const float*)d_in[0];
  const float* Wq  = (const float*)d_in[1];
  const float* bq  = (const float*)d_in[2];
  const float* Wk  = (const float*)d_in[3];
  const float* bk  = (const float*)d_in[4];
  const float* Wv  = (const float*)d_in[5];
  const float* bv  = (const float*)d_in[6];
  const float* gnw = (const float*)d_in[7];
  const float* gnb = (const float*)d_in[8];
  float* out = (float*)d_out;

  const size_t per = (size_t)NB * NC * NHW;  // 4,718,592 floats
  float* qws = (float*)d_ws;
  float* kws = qws + per;
  float* vws = kws + per;
  float* scale = vws + per;      // NB*NC
  float* shift = scale + NB * NC;

  hipLaunchKernelGGL(k_gn_stats, dim3(NB * NG), dim3(256), 0, stream,
                     x, gnw, gnb, scale, shift);
  hipLaunchKernelGGL(k_qkv, dim3(NHW / 64, NC / 64, NB * 3), dim3(256), 0,
                     stream, x, Wq, bq, Wk, bk, Wv, bv, scale, shift,
                     qws, kws, vws);
  const size_t smem = (size_t)(16384 + 16640 + 4160 + 64) * 4;  // 148,992 B
  (void)hipFuncSetAttribute((const void*)k_attn,
                            hipFuncAttributeMaxDynamicSharedMemorySize,
                            (int)smem);
  hipLaunchKernelGGL(k_attn, dim3(NHW / 64, NB), dim3(256), smem, stream,
                     qws, kws, vws, out);
}

// Round 2
// 737.628 us; speedup vs baseline: 3.5103x; 3.5103x over previous
//
#include <hip/hip_runtime.h>
#include <math.h>

#define NB 8
#define NC 256
#define NHW 2304
#define NG 32
#define CPG 8            // NC / NG
#define GN_EPS 1e-5f
#define ATT_SCALE 0.0625f  // 1/sqrt(256)

typedef __bf16 bf16x8 __attribute__((ext_vector_type(8)));
typedef __bf16 bf16x4 __attribute__((ext_vector_type(4)));
typedef float f32x4 __attribute__((ext_vector_type(4)));

// ---------------------------------------------------------------------------
// Kernel 1: GroupNorm statistics -> per-channel scale/shift (fp32, unchanged)
// ---------------------------------------------------------------------------
__global__ __launch_bounds__(256) void k_gn_stats(
    const float* __restrict__ x, const float* __restrict__ gn_w,
    const float* __restrict__ gn_b, float* __restrict__ scale,
    float* __restrict__ shift) {
  int bg = blockIdx.x;  // b*NG + g
  const float4* base = (const float4*)(x + (size_t)bg * CPG * NHW);
  const int n4 = CPG * NHW / 4;  // 4608
  float s = 0.f, ss = 0.f;
  for (int i = threadIdx.x; i < n4; i += 256) {
    float4 v = base[i];
    s  += v.x + v.y + v.z + v.w;
    ss += v.x * v.x + v.y * v.y + v.z * v.z + v.w * v.w;
  }
  for (int off = 32; off > 0; off >>= 1) {
    s  += __shfl_down(s, off);
    ss += __shfl_down(ss, off);
  }
  __shared__ float red[8];
  int wv = threadIdx.x >> 6, ln = threadIdx.x & 63;
  if (ln == 0) { red[wv] = s; red[4 + wv] = ss; }
  __syncthreads();
  if (threadIdx.x < CPG) {
    float S  = red[0] + red[1] + red[2] + red[3];
    float SS = red[4] + red[5] + red[6] + red[7];
    const float inv_n = 1.f / (float)(CPG * NHW);
    float mean = S * inv_n;
    float var  = SS * inv_n - mean * mean;
    float rstd = rsqrtf(var + GN_EPS);
    int b = bg / NG, g = bg % NG;
    int c = g * CPG + threadIdx.x;
    float sc = gn_w[c] * rstd;
    scale[b * NC + c] = sc;
    shift[b * NC + c] = gn_b[c] - mean * sc;
  }
}

// ---------------------------------------------------------------------------
// Kernel 2: fused GN + all three 1x1 convs in one pass (fp32 compute).
// Writes bf16 outputs in MFMA-friendly layouts:
//   qT,kT: [b][p][c] (c contiguous)  -- A/B fragment loads want k=c contiguous
//   v:     [b][c][p] (p contiguous)  -- PV A-fragment wants k=jk contiguous
// grid: (NHW/64, NC/64, NB), block 256. Tile 64x64, K-chunks of 16.
// ---------------------------------------------------------------------------
__global__ __launch_bounds__(256) void k_qkv(
    const float* __restrict__ x,
    const float* __restrict__ Wq, const float* __restrict__ bq,
    const float* __restrict__ Wk, const float* __restrict__ bk,
    const float* __restrict__ Wv, const float* __restrict__ bv,
    const float* __restrict__ scale, const float* __restrict__ shift,
    __bf16* __restrict__ qT, __bf16* __restrict__ kT,
    __bf16* __restrict__ vbuf) {
  __shared__ float xl[16 * 64];  // [c][p] normalized
  __shared__ float wq[16 * 64];  // [c][o]
  __shared__ float wk[16 * 64];
  __shared__ float wvs[16 * 64];
  int p0 = blockIdx.x * 64;
  int o0 = blockIdx.y * 64;
  int b = blockIdx.z;
  int tid = threadIdx.x;
  int tx = tid & 15, ty = tid >> 4;   // 16x16 thread grid
  int lo = tid & 63, lc = tid >> 6;   // loader indices
  float accq[4][4], acck[4][4], accv[4][4];
#pragma unroll
  for (int i = 0; i < 4; ++i)
#pragma unroll
    for (int j = 0; j < 4; ++j) { accq[i][j] = 0.f; acck[i][j] = 0.f; accv[i][j] = 0.f; }
  const float* xb = x + (size_t)b * NC * NHW;
  const float* scb = scale + b * NC;
  const float* shb = shift + b * NC;
  for (int c0 = 0; c0 < NC; c0 += 16) {
    __syncthreads();
#pragma unroll
    for (int r = 0; r < 4; ++r) {
      int c = lc + 4 * r;
      int cg = c0 + c;
      xl[c * 64 + lo]  = xb[(size_t)cg * NHW + p0 + lo] * scb[cg] + shb[cg];
      wq[c * 64 + lo]  = Wq[(size_t)(o0 + lo) * NC + cg];
      wk[c * 64 + lo]  = Wk[(size_t)(o0 + lo) * NC + cg];
      wvs[c * 64 + lo] = Wv[(size_t)(o0 + lo) * NC + cg];
    }
    __syncthreads();
#pragma unroll
    for (int kk = 0; kk < 16; ++kk) {
      float4 xty = *(const float4*)&xl[kk * 64 + 4 * ty];
      float4 xtx = *(const float4*)&xl[kk * 64 + 4 * tx];
      float4 wqv = *(const float4*)&wq[kk * 64 + 4 * tx];
      float4 wkv = *(const float4*)&wk[kk * 64 + 4 * tx];
      float4 wvv = *(const float4*)&wvs[kk * 64 + 4 * ty];
      float xt[4] = {xty.x, xty.y, xty.z, xty.w};
      float xx[4] = {xtx.x, xtx.y, xtx.z, xtx.w};
      float aq[4] = {wqv.x, wqv.y, wqv.z, wqv.w};
      float ak[4] = {wkv.x, wkv.y, wkv.z, wkv.w};
      float av[4] = {wvv.x, wvv.y, wvv.z, wvv.w};
#pragma unroll
      for (int i = 0; i < 4; ++i)
#pragma unroll
        for (int j = 0; j < 4; ++j) {
          accq[i][j] += xt[i] * aq[j];   // rows p(ty), cols o(tx)
          acck[i][j] += xt[i] * ak[j];
          accv[i][j] += av[i] * xx[j];   // rows c(ty), cols p(tx)
        }
    }
  }
  float bqr[4], bkr[4];
#pragma unroll
  for (int j = 0; j < 4; ++j) {
    bqr[j] = bq[o0 + 4 * tx + j];
    bkr[j] = bk[o0 + 4 * tx + j];
  }
#pragma unroll
  for (int i = 0; i < 4; ++i) {
    int p = p0 + 4 * ty + i;
    bf16x4 qv, kv;
#pragma unroll
    for (int j = 0; j < 4; ++j) {
      qv[j] = (__bf16)(accq[i][j] + bqr[j]);
      kv[j] = (__bf16)(acck[i][j] + bkr[j]);
    }
    *(bf16x4*)&qT[((size_t)b * NHW + p) * NC + o0 + 4 * tx] = qv;
    *(bf16x4*)&kT[((size_t)b * NHW + p) * NC + o0 + 4 * tx] = kv;
    int c = o0 + 4 * ty + i;
    float bvc = bv[c];
    bf16x4 vv4;
#pragma unroll
    for (int j = 0; j < 4; ++j) vv4[j] = (__bf16)(accv[i][j] + bvc);
    *(bf16x4*)&vbuf[((size_t)b * NC + c) * NHW + p0 + 4 * tx] = vv4;
  }
}

// ---------------------------------------------------------------------------
// Kernel 3: MFMA flash attention. 1 wave/block, 16 queries/wave, all keys.
//   S-tile:  mfma(Q-frag, K-frag)   -> S[j=16][jk=64]  (4 n-tiles x 8 k-steps)
//   P = exp(S/16) -> bf16 -> LDS [16][72]
//   O^T-tile: mfma(V-frag, P-frag)  -> O^T[c][j], 16 c-tiles x 2 k-steps
// No max-subtraction (|scores| <= ~1), denominators via shfl_xor row sums.
// grid: (NHW/16, NB), block 64.
// ---------------------------------------------------------------------------
__global__ __launch_bounds__(64) void k_attn(
    const __bf16* __restrict__ qT, const __bf16* __restrict__ kT,
    const __bf16* __restrict__ vbuf, float* __restrict__ out) {
  __shared__ __bf16 p_lds[16 * 72];  // [j][jk], stride 72 (pad: 4-way writes)
  __shared__ float l_sh[16];
  int q0 = blockIdx.x * 16;
  int b = blockIdx.y;
  int lane = threadIdx.x;
  int col = lane & 15, quad = lane >> 4;

  // Q fragments: A[m=j][k=c], lane m=col reads 8 contiguous c per k-step
  const __bf16* qrow = qT + ((size_t)b * NHW + q0 + col) * NC + quad * 8;
  bf16x8 qf[8];
#pragma unroll
  for (int ks = 0; ks < 8; ++ks) qf[ks] = *(const bf16x8*)(qrow + ks * 32);

  f32x4 oacc[16];
#pragma unroll
  for (int nt = 0; nt < 16; ++nt) oacc[nt] = (f32x4){0.f, 0.f, 0.f, 0.f};
  float lacc[4] = {0.f, 0.f, 0.f, 0.f};

  const __bf16* kbase = kT + ((size_t)b * NHW + col) * NC + quad * 8;
  const __bf16* vbase = vbuf + ((size_t)b * NC + col) * NHW + quad * 8;

  for (int kt = 0; kt < NHW; kt += 64) {
    // ---- S = Q^T K ----
    f32x4 sacc[4];
#pragma unroll
    for (int nt = 0; nt < 4; ++nt) sacc[nt] = (f32x4){0.f, 0.f, 0.f, 0.f};
    const __bf16* kp = kbase + (size_t)kt * NC;
#pragma unroll
    for (int nt = 0; nt < 4; ++nt) {
      const __bf16* kr = kp + (size_t)nt * 16 * NC;
#pragma unroll
      for (int ks = 0; ks < 8; ++ks) {
        bf16x8 kf = *(const bf16x8*)(kr + ks * 32);
        sacc[nt] =
            __builtin_amdgcn_mfma_f32_16x16x32_bf16(qf[ks], kf, sacc[nt], 0, 0, 0);
      }
    }
    __syncthreads();  // previous iteration's P reads complete
    // ---- P = exp(S/16), write to LDS, accumulate row sums ----
#pragma unroll
    for (int reg = 0; reg < 4; ++reg) {
      float rs = 0.f;
#pragma unroll
      for (int nt = 0; nt < 4; ++nt) {
        float e = __expf(sacc[nt][reg] * ATT_SCALE);
        p_lds[(quad * 4 + reg) * 72 + nt * 16 + col] = (__bf16)e;
        rs += e;
      }
      rs += __shfl_xor(rs, 1);
      rs += __shfl_xor(rs, 2);
      rs += __shfl_xor(rs, 4);
      rs += __shfl_xor(rs, 8);
      lacc[reg] += rs;  // row (quad*4+reg) sum over this key tile
    }
    __syncthreads();  // P visible
    // ---- O^T += V P^T ----
    const __bf16* vp = vbase + kt;
#pragma unroll
    for (int ks2 = 0; ks2 < 2; ++ks2) {
      bf16x8 pf = *(const bf16x8*)&p_lds[col * 72 + ks2 * 32 + quad * 8];
#pragma unroll
      for (int nt = 0; nt < 16; ++nt) {
        bf16x8 vf = *(const bf16x8*)(vp + (size_t)nt * 16 * NHW + ks2 * 32);
        oacc[nt] =
            __builtin_amdgcn_mfma_f32_16x16x32_bf16(vf, pf, oacc[nt], 0, 0, 0);
      }
    }
  }
  // distribute row sums: lane needs l[j = col]
  if (col == 0) {
#pragma unroll
    for (int r = 0; r < 4; ++r) l_sh[quad * 4 + r] = lacc[r];
  }
  __syncthreads();
  float inv = 1.f / l_sh[col];
  float* ob = out + (size_t)b * NC * NHW;
#pragma unroll
  for (int nt = 0; nt < 16; ++nt)
#pragma unroll
    for (int reg = 0; reg < 4; ++reg) {
      int c = nt * 16 + quad * 4 + reg;
      ob[(size_t)c * NHW + q0 + col] = oacc[nt][reg] * inv;
    }
}

// ---------------------------------------------------------------------------
extern "C" void kernel_launch(void* const* d_in, const int* in_sizes, int n_in,
                              void* d_out, int out_size, void* d_ws,
                              size_t ws_size, hipStream_t stream) {
  const float* x   = (const float*)d_in[0];
  const float* Wq  = (const float*)d_in[1];
  const float* bq  = (const float*)d_in[2];
  const float* Wk  = (const float*)d_in[3];
  const float* bk  = (const float*)d_in[4];
  const float* Wv  = (const float*)d_in[5];
  const float* bv  = (const float*)d_in[6];
  const float* gnw = (const float*)d_in[7];
  const float* gnb = (const float*)d_in[8];
  float* out = (float*)d_out;

  const size_t per = (size_t)NB * NC * NHW;  // 4,718,592 elements
  char* wsb = (char*)d_ws;
  __bf16* qT   = (__bf16*)wsb;                     // per*2 bytes
  __bf16* kT   = (__bf16*)(wsb + per * 2);
  __bf16* vbuf = (__bf16*)(wsb + per * 4);
  float* scale = (float*)(wsb + per * 6);
  float* shift = scale + NB * NC;

  hipLaunchKernelGGL(k_gn_stats, dim3(NB * NG), dim3(256), 0, stream,
                     x, gnw, gnb, scale, shift);
  hipLaunchKernelGGL(k_qkv, dim3(NHW / 64, NC / 64, NB), dim3(256), 0, stream,
                     x, Wq, bq, Wk, bk, Wv, bv, scale, shift, qT, kT, vbuf);
  hipLaunchKernelGGL(k_attn, dim3(NHW / 16, NB), dim3(64), 0, stream,
                     qT, kT, vbuf, out);
}

// Round 3
// 526.316 us; speedup vs baseline: 4.9196x; 1.4015x over previous
//
#include <hip/hip_runtime.h>
#include <math.h>

#define NB 8
#define NC 256
#define NHW 2304
#define NG 32
#define CPG 8            // NC / NG
#define GN_EPS 1e-5f
#define ATT_SCALE 0.0625f  // 1/sqrt(256)

typedef __bf16 bf16x8 __attribute__((ext_vector_type(8)));
typedef __bf16 bf16x4 __attribute__((ext_vector_type(4)));
typedef float f32x4 __attribute__((ext_vector_type(4)));

// ---------------------------------------------------------------------------
// Kernel 0: cast Wq/Wk/Wv fp32 -> bf16. grid (64, 3) x 256 threads.
// ---------------------------------------------------------------------------
__global__ __launch_bounds__(256) void k_wcast(
    const float* __restrict__ Wq, const float* __restrict__ Wk,
    const float* __restrict__ Wv, __bf16* __restrict__ Wqb,
    __bf16* __restrict__ Wkb, __bf16* __restrict__ Wvb) {
  const float* src = blockIdx.y == 0 ? Wq : (blockIdx.y == 1 ? Wk : Wv);
  __bf16* dst = blockIdx.y == 0 ? Wqb : (blockIdx.y == 1 ? Wkb : Wvb);
  int i = blockIdx.x * 256 + threadIdx.x;  // float4 index, 16384 total
  float4 v = ((const float4*)src)[i];
  bf16x4 o;
  o[0] = (__bf16)v.x; o[1] = (__bf16)v.y; o[2] = (__bf16)v.z; o[3] = (__bf16)v.w;
  ((bf16x4*)dst)[i] = o;
}

// ---------------------------------------------------------------------------
// Kernel 1: GroupNorm stats + normalize + transpose to bf16 xnT[b][p][c].
// grid: NB*NG blocks (one per (b,group)), 256 threads.
// ---------------------------------------------------------------------------
__global__ __launch_bounds__(256) void k_gn_xnT(
    const float* __restrict__ x, const float* __restrict__ gn_w,
    const float* __restrict__ gn_b, __bf16* __restrict__ xnT) {
  int bg = blockIdx.x;  // b*NG + g
  int b = bg / NG, g = bg % NG;
  const float4* base = (const float4*)(x + (size_t)bg * CPG * NHW);
  const int n4 = CPG * NHW / 4;  // 4608
  float s = 0.f, ss = 0.f;
  for (int i = threadIdx.x; i < n4; i += 256) {
    float4 v = base[i];
    s  += v.x + v.y + v.z + v.w;
    ss += v.x * v.x + v.y * v.y + v.z * v.z + v.w * v.w;
  }
  for (int off = 32; off > 0; off >>= 1) {
    s  += __shfl_down(s, off);
    ss += __shfl_down(ss, off);
  }
  __shared__ float red[8];
  __shared__ float sc_sh[CPG], sh_sh[CPG];
  int wv = threadIdx.x >> 6, ln = threadIdx.x & 63;
  if (ln == 0) { red[wv] = s; red[4 + wv] = ss; }
  __syncthreads();
  if (threadIdx.x < CPG) {
    float S  = red[0] + red[1] + red[2] + red[3];
    float SS = red[4] + red[5] + red[6] + red[7];
    const float inv_n = 1.f / (float)(CPG * NHW);
    float mean = S * inv_n;
    float var  = SS * inv_n - mean * mean;
    float rstd = rsqrtf(var + GN_EPS);
    int c = g * CPG + threadIdx.x;
    float sc = gn_w[c] * rstd;
    sc_sh[threadIdx.x] = sc;
    sh_sh[threadIdx.x] = gn_b[c] - mean * sc;
  }
  __syncthreads();
  float scr[CPG], shr[CPG];
#pragma unroll
  for (int j = 0; j < CPG; ++j) { scr[j] = sc_sh[j]; shr[j] = sh_sh[j]; }
  int c0 = g * CPG;
  const float* xb = x + ((size_t)b * NC + c0) * NHW;
  for (int p = threadIdx.x; p < NHW; p += 256) {
    bf16x8 v8;
#pragma unroll
    for (int j = 0; j < CPG; ++j)
      v8[j] = (__bf16)(xb[(size_t)j * NHW + p] * scr[j] + shr[j]);
    *(bf16x8*)&xnT[((size_t)b * NHW + p) * NC + c0] = v8;
  }
}

// ---------------------------------------------------------------------------
// Kernel 2: QKV via MFMA. Per wave: one 16-p tile, full 256 o, 3 GEMMs.
//   q/k: D = mfma(W-frag[m=o][k=c], xn-frag[k=c][n=p])  -> qT/kT[b][p][o]
//   v:   D = mfma(xn-frag[m=p][k=c], W-frag[k=c][n=o])  -> vbuf[b][o][p]
// grid: 288 blocks x 256 thr (4 waves); b = blk&7 (XCD swizzle).
// ---------------------------------------------------------------------------
__global__ __launch_bounds__(256) void k_qkv(
    const __bf16* __restrict__ xnT,
    const __bf16* __restrict__ Wqb, const __bf16* __restrict__ Wkb,
    const __bf16* __restrict__ Wvb,
    const float* __restrict__ bq, const float* __restrict__ bk,
    const float* __restrict__ bv,
    __bf16* __restrict__ qT, __bf16* __restrict__ kT,
    __bf16* __restrict__ vbuf) {
  int blk = blockIdx.x;
  int b = blk & 7;
  int w = threadIdx.x >> 6;
  int lane = threadIdx.x & 63;
  int col = lane & 15, quad = lane >> 4;
  int p0 = ((blk >> 3) * 4 + w) * 16;

  const __bf16* xrow = xnT + ((size_t)b * NHW + p0 + col) * NC + quad * 8;
  bf16x8 xf[8];
#pragma unroll
  for (int ks = 0; ks < 8; ++ks) xf[ks] = *(const bf16x8*)(xrow + ks * 32);

  // ---- Q and K (same orientation) ----
#pragma unroll
  for (int t = 0; t < 2; ++t) {
    const __bf16* W = t == 0 ? Wqb : Wkb;
    const float* bias = t == 0 ? bq : bk;
    __bf16* dst = t == 0 ? qT : kT;
    f32x4 acc[16];
#pragma unroll
    for (int ot = 0; ot < 16; ++ot) acc[ot] = (f32x4){0.f, 0.f, 0.f, 0.f};
#pragma unroll
    for (int ot = 0; ot < 16; ++ot) {
      const __bf16* wrow = W + ((size_t)(ot * 16 + col)) * NC + quad * 8;
#pragma unroll
      for (int ks = 0; ks < 8; ++ks) {
        bf16x8 wf = *(const bf16x8*)(wrow + ks * 32);
        acc[ot] = __builtin_amdgcn_mfma_f32_16x16x32_bf16(wf, xf[ks], acc[ot], 0, 0, 0);
      }
    }
    __bf16* drow = dst + ((size_t)b * NHW + p0 + col) * NC;
#pragma unroll
    for (int ot = 0; ot < 16; ++ot) {
      float4 b4 = *(const float4*)&bias[ot * 16 + quad * 4];
      bf16x4 st;
      st[0] = (__bf16)(acc[ot][0] + b4.x);
      st[1] = (__bf16)(acc[ot][1] + b4.y);
      st[2] = (__bf16)(acc[ot][2] + b4.z);
      st[3] = (__bf16)(acc[ot][3] + b4.w);
      *(bf16x4*)&drow[ot * 16 + quad * 4] = st;
    }
  }
  // ---- V (swapped operands -> D[m=p][n=o]) ----
  {
    f32x4 acc[16];
#pragma unroll
    for (int ot = 0; ot < 16; ++ot) acc[ot] = (f32x4){0.f, 0.f, 0.f, 0.f};
#pragma unroll
    for (int ot = 0; ot < 16; ++ot) {
      const __bf16* wrow = Wvb + ((size_t)(ot * 16 + col)) * NC + quad * 8;
#pragma unroll
      for (int ks = 0; ks < 8; ++ks) {
        bf16x8 wf = *(const bf16x8*)(wrow + ks * 32);
        acc[ot] = __builtin_amdgcn_mfma_f32_16x16x32_bf16(xf[ks], wf, acc[ot], 0, 0, 0);
      }
    }
#pragma unroll
    for (int ot = 0; ot < 16; ++ot) {
      float bvc = bv[ot * 16 + col];
      bf16x4 st;
#pragma unroll
      for (int r = 0; r < 4; ++r) st[r] = (__bf16)(acc[ot][r] + bvc);
      *(bf16x4*)&vbuf[((size_t)b * NC + ot * 16 + col) * NHW + p0 + quad * 4] = st;
    }
  }
}

// ---------------------------------------------------------------------------
// Kernel 3: MFMA flash attention, 4-way key-split.
// Block: 256 thr = 4 waves, ONE 16-query tile; wave w handles keys
// kt = w*64, w*64+256, ... (9 tiles each). Partial O^T and row-sums reduced
// through LDS at the end. b = blk&7 -> one batch per XCD (K/V L2-resident).
// grid: 1152 blocks.
// ---------------------------------------------------------------------------
__global__ __launch_bounds__(256) void k_attn(
    const __bf16* __restrict__ qT, const __bf16* __restrict__ kT,
    const __bf16* __restrict__ vbuf, float* __restrict__ out) {
  __shared__ __align__(16) char smem[2 * 4352 * 4];  // 34816 B
  __shared__ float l_red[4][16];
  float* obuf0 = (float*)smem;          // [256][17] f32
  float* obuf1 = obuf0 + 4352;
  int blk = blockIdx.x;
  int b = blk & 7;
  int q0 = (blk >> 3) * 16;
  int w = threadIdx.x >> 6;
  int lane = threadIdx.x & 63;
  int col = lane & 15, quad = lane >> 4;
  __bf16* p_lds = (__bf16*)smem + w * 1152;  // per-wave [16][72]

  const __bf16* qrow = qT + ((size_t)b * NHW + q0 + col) * NC + quad * 8;
  bf16x8 qf[8];
#pragma unroll
  for (int ks = 0; ks < 8; ++ks) qf[ks] = *(const bf16x8*)(qrow + ks * 32);

  f32x4 oacc[16];
#pragma unroll
  for (int nt = 0; nt < 16; ++nt) oacc[nt] = (f32x4){0.f, 0.f, 0.f, 0.f};
  float lacc[4] = {0.f, 0.f, 0.f, 0.f};

  const __bf16* kbase = kT + ((size_t)b * NHW + col) * NC + quad * 8;
  const __bf16* vbase = vbuf + ((size_t)b * NC + col) * NHW + quad * 8;

  for (int kt = w * 64; kt < NHW; kt += 256) {
    // ---- S = Q K^T ----
    f32x4 sacc[4];
#pragma unroll
    for (int nt = 0; nt < 4; ++nt) sacc[nt] = (f32x4){0.f, 0.f, 0.f, 0.f};
    const __bf16* kp = kbase + (size_t)kt * NC;
#pragma unroll
    for (int nt = 0; nt < 4; ++nt) {
      const __bf16* kr = kp + (size_t)nt * 16 * NC;
#pragma unroll
      for (int ks = 0; ks < 8; ++ks) {
        bf16x8 kf = *(const bf16x8*)(kr + ks * 32);
        sacc[nt] = __builtin_amdgcn_mfma_f32_16x16x32_bf16(qf[ks], kf, sacc[nt], 0, 0, 0);
      }
    }
    // ---- P = exp(S/16) -> per-wave LDS; accumulate row sums ----
#pragma unroll
    for (int reg = 0; reg < 4; ++reg) {
      float rs = 0.f;
#pragma unroll
      for (int nt = 0; nt < 4; ++nt) {
        float e = __expf(sacc[nt][reg] * ATT_SCALE);
        p_lds[(quad * 4 + reg) * 72 + nt * 16 + col] = (__bf16)e;
        rs += e;
      }
      rs += __shfl_xor(rs, 1);
      rs += __shfl_xor(rs, 2);
      rs += __shfl_xor(rs, 4);
      rs += __shfl_xor(rs, 8);
      lacc[reg] += rs;
    }
    __asm__ volatile("s_waitcnt lgkmcnt(0)" ::: "memory");  // in-wave P vis.
    // ---- O^T += V P^T ----
    const __bf16* vp = vbase + kt;
#pragma unroll
    for (int ks2 = 0; ks2 < 2; ++ks2) {
      bf16x8 pf = *(const bf16x8*)&p_lds[col * 72 + ks2 * 32 + quad * 8];
#pragma unroll
      for (int nt = 0; nt < 16; ++nt) {
        bf16x8 vf = *(const bf16x8*)(vp + (size_t)nt * 16 * NHW + ks2 * 32);
        oacc[nt] = __builtin_amdgcn_mfma_f32_16x16x32_bf16(vf, pf, oacc[nt], 0, 0, 0);
      }
    }
  }
  if (col == 0) {
#pragma unroll
    for (int reg = 0; reg < 4; ++reg) l_red[w][quad * 4 + reg] = lacc[reg];
  }
  __syncthreads();  // all p_lds reads done; l_red visible
  // ---- O reduction through LDS: w1->obuf0, w3->obuf1; w0+=o0, w2+=o1;
  //      w2->obuf0; w0+=o0; w0 normalizes and stores. ----
  if (w == 1 || w == 3) {
    float* dst = (w == 1) ? obuf0 : obuf1;
#pragma unroll
    for (int nt = 0; nt < 16; ++nt)
#pragma unroll
      for (int reg = 0; reg < 4; ++reg)
        dst[(nt * 16 + quad * 4 + reg) * 17 + col] = oacc[nt][reg];
  }
  __syncthreads();
  if (w == 0 || w == 2) {
    const float* src = (w == 0) ? obuf0 : obuf1;
#pragma unroll
    for (int nt = 0; nt < 16; ++nt)
#pragma unroll
      for (int reg = 0; reg < 4; ++reg)
        oacc[nt][reg] += src[(nt * 16 + quad * 4 + reg) * 17 + col];
  }
  __syncthreads();
  if (w == 2) {
#pragma unroll
    for (int nt = 0; nt < 16; ++nt)
#pragma unroll
      for (int reg = 0; reg < 4; ++reg)
        obuf0[(nt * 16 + quad * 4 + reg) * 17 + col] = oacc[nt][reg];
  }
  __syncthreads();
  if (w == 0) {
    float lsum = l_red[0][col] + l_red[1][col] + l_red[2][col] + l_red[3][col];
    float inv = 1.f / lsum;
    float* ob = out + (size_t)b * NC * NHW;
#pragma unroll
    for (int nt = 0; nt < 16; ++nt)
#pragma unroll
      for (int reg = 0; reg < 4; ++reg) {
        int c = nt * 16 + quad * 4 + reg;
        float o = (oacc[nt][reg] + obuf0[c * 17 + col]) * inv;
        ob[(size_t)c * NHW + q0 + col] = o;
      }
  }
}

// ---------------------------------------------------------------------------
extern "C" void kernel_launch(void* const* d_in, const int* in_sizes, int n_in,
                              void* d_out, int out_size, void* d_ws,
                              size_t ws_size, hipStream_t stream) {
  const float* x   = (const float*)d_in[0];
  const float* Wq  = (const float*)d_in[1];
  const float* bq  = (const float*)d_in[2];
  const float* Wk  = (const float*)d_in[3];
  const float* bk  = (const float*)d_in[4];
  const float* Wv  = (const float*)d_in[5];
  const float* bv  = (const float*)d_in[6];
  const float* gnw = (const float*)d_in[7];
  const float* gnb = (const float*)d_in[8];
  float* out = (float*)d_out;

  const size_t per = (size_t)NB * NC * NHW;  // 4,718,592 elements
  char* wsb = (char*)d_ws;
  __bf16* xnT  = (__bf16*)wsb;                  // per*2 B
  __bf16* qT   = (__bf16*)(wsb + per * 2);
  __bf16* kT   = (__bf16*)(wsb + per * 4);
  __bf16* vbuf = (__bf16*)(wsb + per * 6);
  __bf16* Wqb  = (__bf16*)(wsb + per * 8);
  __bf16* Wkb  = Wqb + NC * NC;
  __bf16* Wvb  = Wkb + NC * NC;

  hipLaunchKernelGGL(k_wcast, dim3(64, 3), dim3(256), 0, stream,
                     Wq, Wk, Wv, Wqb, Wkb, Wvb);
  hipLaunchKernelGGL(k_gn_xnT, dim3(NB * NG), dim3(256), 0, stream,
                     x, gnw, gnb, xnT);
  hipLaunchKernelGGL(k_qkv, dim3(288), dim3(256), 0, stream,
                     xnT, Wqb, Wkb, Wvb, bq, bk, bv, qT, kT, vbuf);
  hipLaunchKernelGGL(k_attn, dim3(1152), dim3(256), 0, stream,
                     qT, kT, vbuf, out);
}

// Round 4
// 359.527 us; speedup vs baseline: 7.2019x; 1.4639x over previous
//
#include <hip/hip_runtime.h>
#include <math.h>

#define NB 8
#define NC 256
#define NHW 2304
#define NG 32
#define CPG 8            // NC / NG
#define GN_EPS 1e-5f
#define ATT_SCALE 0.0625f  // 1/sqrt(256)
#define PSTRIDE 68         // P-tile LDS row stride (bf16): conflict-free writes

typedef __bf16 bf16x8 __attribute__((ext_vector_type(8)));
typedef __bf16 bf16x4 __attribute__((ext_vector_type(4)));
typedef float f32x4 __attribute__((ext_vector_type(4)));

#define MFMA(a, b, c) __builtin_amdgcn_mfma_f32_16x16x32_bf16(a, b, c, 0, 0, 0)

// ---------------------------------------------------------------------------
// Kernel 0: cast Wq/Wk/Wv fp32 -> bf16. grid (64, 3) x 256 threads.
// ---------------------------------------------------------------------------
__global__ __launch_bounds__(256) void k_wcast(
    const float* __restrict__ Wq, const float* __restrict__ Wk,
    const float* __restrict__ Wv, __bf16* __restrict__ Wqb,
    __bf16* __restrict__ Wkb, __bf16* __restrict__ Wvb) {
  const float* src = blockIdx.y == 0 ? Wq : (blockIdx.y == 1 ? Wk : Wv);
  __bf16* dst = blockIdx.y == 0 ? Wqb : (blockIdx.y == 1 ? Wkb : Wvb);
  int i = blockIdx.x * 256 + threadIdx.x;  // float4 index, 16384 total
  float4 v = ((const float4*)src)[i];
  bf16x4 o;
  o[0] = (__bf16)v.x; o[1] = (__bf16)v.y; o[2] = (__bf16)v.z; o[3] = (__bf16)v.w;
  ((bf16x4*)dst)[i] = o;
}

// ---------------------------------------------------------------------------
// Kernel 1: GroupNorm. Group slab (8ch x 2304 = 72 KB) staged in LDS so x is
// read from HBM exactly once; stats accumulated during the staging loop.
// grid: NB*NG = 256 blocks, 256 threads. Dynamic LDS 73728 B.
// ---------------------------------------------------------------------------
__global__ __launch_bounds__(256) void k_gn_xnT(
    const float* __restrict__ x, const float* __restrict__ gn_w,
    const float* __restrict__ gn_b, __bf16* __restrict__ xnT) {
  extern __shared__ float xl[];  // [CPG][NHW]
  __shared__ float red[8];
  __shared__ float sc_sh[CPG], sh_sh[CPG];
  int bg = blockIdx.x;
  int b = bg / NG, g = bg % NG;
  const float4* base = (const float4*)(x + (size_t)bg * CPG * NHW);
  float4* xl4 = (float4*)xl;
  const int n4 = CPG * NHW / 4;  // 4608
  float s = 0.f, ss = 0.f;
  for (int i = threadIdx.x; i < n4; i += 256) {
    float4 v = base[i];
    xl4[i] = v;
    s  += v.x + v.y + v.z + v.w;
    ss += v.x * v.x + v.y * v.y + v.z * v.z + v.w * v.w;
  }
  for (int off = 32; off > 0; off >>= 1) {
    s  += __shfl_down(s, off);
    ss += __shfl_down(ss, off);
  }
  int wv = threadIdx.x >> 6, ln = threadIdx.x & 63;
  if (ln == 0) { red[wv] = s; red[4 + wv] = ss; }
  __syncthreads();
  if (threadIdx.x < CPG) {
    float S  = red[0] + red[1] + red[2] + red[3];
    float SS = red[4] + red[5] + red[6] + red[7];
    const float inv_n = 1.f / (float)(CPG * NHW);
    float mean = S * inv_n;
    float var  = SS * inv_n - mean * mean;
    float rstd = rsqrtf(var + GN_EPS);
    int c = g * CPG + threadIdx.x;
    float sc = gn_w[c] * rstd;
    sc_sh[threadIdx.x] = sc;
    sh_sh[threadIdx.x] = gn_b[c] - mean * sc;
  }
  __syncthreads();
  float scr[CPG], shr[CPG];
#pragma unroll
  for (int j = 0; j < CPG; ++j) { scr[j] = sc_sh[j]; shr[j] = sh_sh[j]; }
  int c0 = g * CPG;
  for (int p = threadIdx.x; p < NHW; p += 256) {
    bf16x8 v8;
#pragma unroll
    for (int j = 0; j < CPG; ++j)
      v8[j] = (__bf16)(xl[j * NHW + p] * scr[j] + shr[j]);
    *(bf16x8*)&xnT[((size_t)b * NHW + p) * NC + c0] = v8;
  }
}

// ---------------------------------------------------------------------------
// Kernel 2: QKV via MFMA, o-quarter per block for occupancy.
// Block: 4 waves; wave w: p-tile p0 = (pg*4+w)*16, o in [oq*64, +64).
// All 4 waves read identical W fragments (L1 reuse).
// grid: 36 p-groups x 4 o-quarters x 8 b = 1152 blocks; b = blk&7 (XCD).
// ---------------------------------------------------------------------------
__global__ __launch_bounds__(256) void k_qkv(
    const __bf16* __restrict__ xnT,
    const __bf16* __restrict__ Wqb, const __bf16* __restrict__ Wkb,
    const __bf16* __restrict__ Wvb,
    const float* __restrict__ bq, const float* __restrict__ bk,
    const float* __restrict__ bv,
    __bf16* __restrict__ qT, __bf16* __restrict__ kT,
    __bf16* __restrict__ vbuf) {
  int blk = blockIdx.x;
  int b = blk & 7;
  int r = blk >> 3;
  int oq = r & 3;
  int pg = r >> 2;
  int w = threadIdx.x >> 6;
  int lane = threadIdx.x & 63;
  int col = lane & 15, quad = lane >> 4;
  int p0 = (pg * 4 + w) * 16;
  int o0 = oq * 64;

  const __bf16* xrow = xnT + ((size_t)b * NHW + p0 + col) * NC + quad * 8;
  bf16x8 xf[8];
#pragma unroll
  for (int ks = 0; ks < 8; ++ks) xf[ks] = *(const bf16x8*)(xrow + ks * 32);

  // ---- Q and K: D[m=o][n=p] ----
#pragma unroll
  for (int t = 0; t < 2; ++t) {
    const __bf16* W = t == 0 ? Wqb : Wkb;
    const float* bias = t == 0 ? bq : bk;
    __bf16* dst = t == 0 ? qT : kT;
    __bf16* drow = dst + ((size_t)b * NHW + p0 + col) * NC + o0;
#pragma unroll
    for (int ot = 0; ot < 4; ++ot) {
      f32x4 acc = (f32x4){0.f, 0.f, 0.f, 0.f};
      const __bf16* wrow = W + ((size_t)(o0 + ot * 16 + col)) * NC + quad * 8;
#pragma unroll
      for (int ks = 0; ks < 8; ++ks) {
        bf16x8 wf = *(const bf16x8*)(wrow + ks * 32);
        acc = MFMA(wf, xf[ks], acc);
      }
      float4 b4 = *(const float4*)&bias[o0 + ot * 16 + quad * 4];
      bf16x4 st;
      st[0] = (__bf16)(acc[0] + b4.x);
      st[1] = (__bf16)(acc[1] + b4.y);
      st[2] = (__bf16)(acc[2] + b4.z);
      st[3] = (__bf16)(acc[3] + b4.w);
      *(bf16x4*)&drow[ot * 16 + quad * 4] = st;
    }
  }
  // ---- V: swapped operands -> D[m=p][n=o]; store to vbuf[c][p] ----
#pragma unroll
  for (int ot = 0; ot < 4; ++ot) {
    f32x4 acc = (f32x4){0.f, 0.f, 0.f, 0.f};
    const __bf16* wrow = Wvb + ((size_t)(o0 + ot * 16 + col)) * NC + quad * 8;
#pragma unroll
    for (int ks = 0; ks < 8; ++ks) {
      bf16x8 wf = *(const bf16x8*)(wrow + ks * 32);
      acc = MFMA(xf[ks], wf, acc);
    }
    float bvc = bv[o0 + ot * 16 + col];
    bf16x4 st;
#pragma unroll
    for (int reg = 0; reg < 4; ++reg) st[reg] = (__bf16)(acc[reg] + bvc);
    *(bf16x4*)&vbuf[((size_t)b * NC + o0 + ot * 16 + col) * NHW + p0 + quad * 4] = st;
  }
}

// ---------------------------------------------------------------------------
// Kernel 3: MFMA flash attention, 64 queries/block, K/V read once per block.
//   S: 2x2 wave split (wq = query half, wk = key half); Q in registers.
//   P: bf16 in LDS [64][68] (conflict-free writes, balanced b128 reads).
//   PV: channel split (wave w owns c in [w*64,+64)) -> private O, no reduce.
// grid: 36 q-groups x 8 b = 288 blocks; b = blk&7 (XCD locality).
// ---------------------------------------------------------------------------
__global__ __launch_bounds__(256, 2) void k_attn(
    const __bf16* __restrict__ qT, const __bf16* __restrict__ kT,
    const __bf16* __restrict__ vbuf, float* __restrict__ out) {
  __shared__ __bf16 p_lds[64 * PSTRIDE];  // 8704 B
  __shared__ float l_red[2][64];
  int blk = blockIdx.x;
  int b = blk & 7;
  int q0 = (blk >> 3) * 64;
  int w = threadIdx.x >> 6;
  int wq = w >> 1, wk = w & 1;
  int lane = threadIdx.x & 63;
  int col = lane & 15, quad = lane >> 4;

  // Q fragments: rows q0+wq*32 .. +32 (2 m-tiles x 8 ks) = 64 VGPRs
  bf16x8 qf[2][8];
  {
    const __bf16* qrow =
        qT + ((size_t)b * NHW + q0 + wq * 32 + col) * NC + quad * 8;
#pragma unroll
    for (int mt = 0; mt < 2; ++mt)
#pragma unroll
      for (int ks = 0; ks < 8; ++ks)
        qf[mt][ks] = *(const bf16x8*)(qrow + (size_t)mt * 16 * NC + ks * 32);
  }

  f32x4 oacc[4][4];  // [ct][qt]: c = w*64+ct*16+quad*4+reg, q = qt*16+col
#pragma unroll
  for (int ct = 0; ct < 4; ++ct)
#pragma unroll
    for (int qt = 0; qt < 4; ++qt) oacc[ct][qt] = (f32x4){0.f, 0.f, 0.f, 0.f};
  float lacc[2][4] = {{0.f, 0.f, 0.f, 0.f}, {0.f, 0.f, 0.f, 0.f}};

  const __bf16* kbase =
      kT + ((size_t)b * NHW + wk * 32 + col) * NC + quad * 8;
  const __bf16* vbase =
      vbuf + ((size_t)b * NC + w * 64 + col) * NHW + quad * 8;

  for (int kt = 0; kt < NHW; kt += 64) {
    // ---- S[32q x 32k] for this wave's quarter ----
    f32x4 sacc[2][2];  // [nt][mt]
#pragma unroll
    for (int nt = 0; nt < 2; ++nt)
#pragma unroll
      for (int mt = 0; mt < 2; ++mt) sacc[nt][mt] = (f32x4){0.f, 0.f, 0.f, 0.f};
    const __bf16* kp = kbase + (size_t)kt * NC;
#pragma unroll
    for (int nt = 0; nt < 2; ++nt) {
#pragma unroll
      for (int ks = 0; ks < 8; ++ks) {
        bf16x8 kf = *(const bf16x8*)(kp + (size_t)nt * 16 * NC + ks * 32);
        sacc[nt][0] = MFMA(qf[0][ks], kf, sacc[nt][0]);
        sacc[nt][1] = MFMA(qf[1][ks], kf, sacc[nt][1]);
      }
    }
    __syncthreads();  // previous tile's PV reads of p_lds complete
    // ---- P = exp(S/16) -> LDS; row-sum partials via shfl ----
#pragma unroll
    for (int mt = 0; mt < 2; ++mt) {
#pragma unroll
      for (int reg = 0; reg < 4; ++reg) {
        float e0 = __expf(sacc[0][mt][reg] * ATT_SCALE);
        float e1 = __expf(sacc[1][mt][reg] * ATT_SCALE);
        int row = wq * 32 + mt * 16 + quad * 4 + reg;
        p_lds[row * PSTRIDE + wk * 32 + col] = (__bf16)e0;
        p_lds[row * PSTRIDE + wk * 32 + 16 + col] = (__bf16)e1;
        float rs = e0 + e1;
        rs += __shfl_xor(rs, 1);
        rs += __shfl_xor(rs, 2);
        rs += __shfl_xor(rs, 4);
        rs += __shfl_xor(rs, 8);
        lacc[mt][reg] += rs;
      }
    }
    __syncthreads();  // P visible to all waves
    // ---- O[c-quarter] += V P^T ----
    const __bf16* vp = vbase + kt;
#pragma unroll
    for (int ks2 = 0; ks2 < 2; ++ks2) {
      bf16x8 pf[4];
#pragma unroll
      for (int qt = 0; qt < 4; ++qt)
        pf[qt] = *(const bf16x8*)&p_lds[(qt * 16 + col) * PSTRIDE + ks2 * 32 +
                                        quad * 8];
#pragma unroll
      for (int ct = 0; ct < 4; ++ct) {
        bf16x8 vf = *(const bf16x8*)(vp + (size_t)ct * 16 * NHW + ks2 * 32);
#pragma unroll
        for (int qt = 0; qt < 4; ++qt)
          oacc[ct][qt] = MFMA(vf, pf[qt], oacc[ct][qt]);
      }
    }
  }
  // ---- combine row sums across key halves ----
  if (col == 0) {
#pragma unroll
    for (int mt = 0; mt < 2; ++mt)
#pragma unroll
      for (int reg = 0; reg < 4; ++reg)
        l_red[wk][wq * 32 + mt * 16 + quad * 4 + reg] = lacc[mt][reg];
  }
  __syncthreads();
  float inv[4];
#pragma unroll
  for (int qt = 0; qt < 4; ++qt) {
    int qr = qt * 16 + col;
    inv[qt] = 1.f / (l_red[0][qr] + l_red[1][qr]);
  }
  float* ob = out + (size_t)b * NC * NHW + q0;
#pragma unroll
  for (int ct = 0; ct < 4; ++ct)
#pragma unroll
    for (int reg = 0; reg < 4; ++reg) {
      int c = w * 64 + ct * 16 + quad * 4 + reg;
#pragma unroll
      for (int qt = 0; qt < 4; ++qt)
        ob[(size_t)c * NHW + qt * 16 + col] = oacc[ct][qt][reg] * inv[qt];
    }
}

// ---------------------------------------------------------------------------
extern "C" void kernel_launch(void* const* d_in, const int* in_sizes, int n_in,
                              void* d_out, int out_size, void* d_ws,
                              size_t ws_size, hipStream_t stream) {
  const float* x   = (const float*)d_in[0];
  const float* Wq  = (const float*)d_in[1];
  const float* bq  = (const float*)d_in[2];
  const float* Wk  = (const float*)d_in[3];
  const float* bk  = (const float*)d_in[4];
  const float* Wv  = (const float*)d_in[5];
  const float* bv  = (const float*)d_in[6];
  const float* gnw = (const float*)d_in[7];
  const float* gnb = (const float*)d_in[8];
  float* out = (float*)d_out;

  const size_t per = (size_t)NB * NC * NHW;  // 4,718,592 elements
  char* wsb = (char*)d_ws;
  __bf16* xnT  = (__bf16*)wsb;                  // per*2 B
  __bf16* qT   = (__bf16*)(wsb + per * 2);
  __bf16* kT   = (__bf16*)(wsb + per * 4);
  __bf16* vbuf = (__bf16*)(wsb + per * 6);
  __bf16* Wqb  = (__bf16*)(wsb + per * 8);
  __bf16* Wkb  = Wqb + NC * NC;
  __bf16* Wvb  = Wkb + NC * NC;

  hipLaunchKernelGGL(k_wcast, dim3(64, 3), dim3(256), 0, stream,
                     Wq, Wk, Wv, Wqb, Wkb, Wvb);
  const int gn_smem = CPG * NHW * 4;  // 73728 B dynamic
  (void)hipFuncSetAttribute((const void*)k_gn_xnT,
                            hipFuncAttributeMaxDynamicSharedMemorySize,
                            gn_smem);
  hipLaunchKernelGGL(k_gn_xnT, dim3(NB * NG), dim3(256), gn_smem, stream,
                     x, gnw, gnb, xnT);
  hipLaunchKernelGGL(k_qkv, dim3(1152), dim3(256), 0, stream,
                     xnT, Wqb, Wkb, Wvb, bq, bk, bv, qT, kT, vbuf);
  hipLaunchKernelGGL(k_attn, dim3(288), dim3(256), 0, stream,
                     qT, kT, vbuf, out);
}